// Round 3
// baseline (29686.407 us; speedup 1.0000x reference)
//
#include <hip/hip_runtime.h>
#include <math.h>

// Problem constants
#define Bb    64
#define Ss    1024
#define CINc  256
#define Hh    512
#define Kk    768          // CIN + H
#define NBLK  256          // one block per CU; each owns 2 hidden units (8 gate rows)
#define NTHR  256          // 4 waves
#define CHUNK 128          // k-floats per staged chunk
#define NCHUNK 6
#define SLOTS 8            // 4 gates x 2 units
#define C4    32           // float4 columns per chunk row

// ws layout: [wt: NBLK*SLOTS*Kk f32][hbuf: 2*B*H f32][ctr: 8 x 64B]
#define WT_FLOATS   (NBLK * SLOTS * Kk)
#define HBUF_FLOATS (2 * Bb * Hh)
#define NCTR 8
#define CTR_STRIDE 16      // uints -> 64 B apart

// Extract center-tap weights into block-major layout:
// wt[bl][s][k] = W[(col*Kk + k)*3 + 1], col = 2*bl + (s&1) + Hh*(s>>1)
__global__ void extract_weights(const float* __restrict__ W, float* __restrict__ wt) {
    int total = WT_FLOATS;
    for (int idx = blockIdx.x * blockDim.x + threadIdx.x; idx < total;
         idx += gridDim.x * blockDim.x) {
        int k    = idx % Kk;
        int rest = idx / Kk;
        int s    = rest % SLOTS;
        int bl   = rest / SLOTS;
        int col  = 2 * bl + (s & 1) + Hh * (s >> 1);
        wt[idx] = W[((size_t)col * Kk + k) * 3 + 1];
    }
}

__device__ __forceinline__ float sigf(float v) { return 1.0f / (1.0f + expf(-v)); }

__device__ __forceinline__ void wait_vm0() {
    asm volatile("s_waitcnt vmcnt(0)" ::: "memory");
}
// LLC-coherent load/store for the h exchange (bypass L1+L2, keep L2 warm for W/x).
__device__ __forceinline__ float4 load4_llc(const float* p) {
    float4 v;
    asm volatile("global_load_dwordx4 %0, %1, off sc0 sc1" : "=&v"(v) : "v"(p) : "memory");
    return v;
}
__device__ __forceinline__ void store_llc(float* p, float v) {
    asm volatile("global_store_dword %0, %1, off sc0 sc1" :: "v"(p), "v"(v) : "memory");
}

__global__ __launch_bounds__(NTHR, 1) void lstm_coop(
    const float* __restrict__ x,    // [B,S,CIN]
    const float* __restrict__ bias, // [4H]
    const float* __restrict__ h0,   // [B,H]
    const float* __restrict__ c0,   // [B,H]
    const float* __restrict__ wt,   // [NBLK][SLOTS][Kk]  (global; wave-uniform reads)
    float* __restrict__ hbuf,       // [2][B][H]  (LLC-coherent access only)
    unsigned* ctr,                  // 8 striped barrier counters
    float* __restrict__ out)        // [B,S,H] ++ [B,H] ++ [B,H]
{
    // A-tile: float4, XOR-swizzled column c' = c ^ (b&31). Double-buffered.
    __shared__ float4 a4[2][Bb][C4];      // 64 KB
    __shared__ float  g_lds[SLOTS][Bb];   // 2 KB

    const int tid  = threadIdx.x;
    const int lane = tid & 63;
    const int q    = __builtin_amdgcn_readfirstlane(tid >> 6);  // wave 0..3
    const int bl   = blockIdx.x;
    const int u0   = 2 * bl;

    // Weight rows for slots q (i/f) and q+4 (g/o): wave-uniform global pointers.
    const float* w0 = wt + ((size_t)bl * SLOTS + q) * Kk;
    const float* w1 = w0 + 4 * (size_t)Kk;

    const int   colA  = u0 + (q & 1) + Hh * (q >> 1);
    const float biasA = bias[colA];
    const float biasB = bias[colA + 2 * Hh];

    // init hbuf[0] = h0 with LLC-coherent stores
    for (int i = bl * NTHR + tid; i < Bb * Hh; i += NBLK * NTHR) store_llc(&hbuf[i], h0[i]);
    wait_vm0();

    float cstate = 0.f;
    int   ucell  = 0;
    if (q < 2) {
        ucell  = u0 + q;
        cstate = c0[(size_t)lane * Hh + ucell];
    }

    __syncthreads();
    // barrier phase 1 (init visible)
    if (tid == 0) __hip_atomic_fetch_add(&ctr[(bl & 7) * CTR_STRIDE], 1u,
                                         __ATOMIC_RELAXED, __HIP_MEMORY_SCOPE_AGENT);
    if (tid < NCTR) {
        while (__hip_atomic_load(&ctr[tid * CTR_STRIDE],
                                 __ATOMIC_RELAXED, __HIP_MEMORY_SCOPE_AGENT) < 32u)
            __builtin_amdgcn_s_sleep(2);
    }
    __atomic_signal_fence(__ATOMIC_SEQ_CST);
    __syncthreads();

    // staging mapping: wave q stages rows bb = 16q + (lane&15); col-phase sub = lane>>4.
    // Wave's global access per j: 16 rows x 64 B contiguous (coalesced), and LDS
    // b128 writes are bank-conflict-free under the XOR swizzle.
    const int bb  = 16 * q + (lane & 15);
    const int sub = lane >> 4;
    const int bsw = bb & 31;
    const int lsw = lane & 31;

    const float* xrow_base = x + (size_t)bb * Ss * CINc + 4 * sub;

    float4 v[8];
    #pragma unroll
    for (int j = 0; j < 8; ++j) v[j] = *(const float4*)(xrow_base + 16 * j);  // t=0, chunk 0

    for (int t = 0; t < Ss; ++t) {
        const int cur = t & 1;
        const float* hcur = hbuf + (size_t)cur * Bb * Hh;
        float*       hnxt = hbuf + (size_t)(cur ^ 1) * Bb * Hh;
        const float* xrow = xrow_base + (size_t)t * CINc;
        const float* hrow = hcur + (size_t)bb * Hh + 4 * sub;

        // launder weight pointers each step: blocks LICM from hoisting w-loads
        const float* w0p = w0;
        const float* w1p = w1;
        asm volatile("" : "+s"(w0p), "+s"(w1p));

        float accA = biasA;
        float accB = biasB;

        #pragma unroll 1
        for (int ch = 0; ch < NCHUNK; ++ch) {
            if (ch >= 2) wait_vm0();           // drain my asm h-loads before use
            float4 (*abuf)[C4] = a4[ch & 1];
            #pragma unroll
            for (int j = 0; j < 8; ++j) abuf[bb][(sub + 4 * j) ^ bsw] = v[j];
            __syncthreads();                   // single barrier per chunk (dbuf)

            // prefetch next chunk (overlaps compute below)
            if (ch < NCHUNK - 1) {
                if (ch + 1 < 2) {
                    const float* s0 = xrow + (ch + 1) * CHUNK;
                    #pragma unroll
                    for (int j = 0; j < 8; ++j) v[j] = *(const float4*)(s0 + 16 * j);
                } else {
                    const float* s0 = hrow + (ch + 1) * CHUNK - CINc;
                    #pragma unroll
                    for (int j = 0; j < 8; ++j) v[j] = load4_llc(s0 + 16 * j);
                }
            } else {
                // prefetch x chunk 0 of t+1 (flies during epilogue + grid barrier)
                const float* s0 = xrow_base + (size_t)((t + 1 < Ss) ? t + 1 : t) * CINc;
                #pragma unroll
                for (int j = 0; j < 8; ++j) v[j] = *(const float4*)(s0 + 16 * j);
            }

            const float* wa0 = w0p + ch * CHUNK;
            const float* wb0 = w1p + ch * CHUNK;
            #pragma unroll
            for (int c = 0; c < C4; ++c) {
                float4 av = abuf[lane][c ^ lsw];            // 1 ds_read_b128, conflict-free
                float4 wa = *(const float4*)(wa0 + 4 * c);  // wave-uniform global (SMEM/VMEM)
                float4 wb = *(const float4*)(wb0 + 4 * c);
                accA = fmaf(av.x, wa.x, accA);
                accA = fmaf(av.y, wa.y, accA);
                accA = fmaf(av.z, wa.z, accA);
                accA = fmaf(av.w, wa.w, accA);
                accB = fmaf(av.x, wb.x, accB);
                accB = fmaf(av.y, wb.y, accB);
                accB = fmaf(av.z, wb.z, accB);
                accB = fmaf(av.w, wb.w, accB);
            }
        }

        g_lds[q][lane]     = accA;
        g_lds[q + 4][lane] = accB;
        __syncthreads();

        if (q < 2) {   // waves 0,1: cell update for unit u0+q, b = lane
            float iv = sigf(g_lds[0 + q][lane]);
            float fv = sigf(g_lds[2 + q][lane]);
            float gv = tanhf(g_lds[4 + q][lane]);
            float ov = sigf(g_lds[6 + q][lane]);
            cstate = fv * cstate + iv * gv;
            float hv = ov * tanhf(cstate);
            store_llc(&hnxt[(size_t)lane * Hh + ucell], hv);
            out[((size_t)lane * Ss + t) * Hh + ucell] = hv;
            if (t == Ss - 1) {
                out[(size_t)Bb * Ss * Hh + (size_t)lane * Hh + ucell] = hv;
                out[(size_t)Bb * Ss * Hh + (size_t)Bb * Hh + (size_t)lane * Hh + ucell] = cstate;
            }
        }
        wait_vm0();        // drain my h stores before arrival
        __syncthreads();

        // grid barrier: striped relaxed counters, no HW cache fences
        if (tid == 0) __hip_atomic_fetch_add(&ctr[(bl & 7) * CTR_STRIDE], 1u,
                                             __ATOMIC_RELAXED, __HIP_MEMORY_SCOPE_AGENT);
        const unsigned target = 32u * (unsigned)(t + 2);
        if (tid < NCTR) {
            while (__hip_atomic_load(&ctr[tid * CTR_STRIDE],
                                     __ATOMIC_RELAXED, __HIP_MEMORY_SCOPE_AGENT) < target)
                __builtin_amdgcn_s_sleep(2);
        }
        __atomic_signal_fence(__ATOMIC_SEQ_CST);
        __syncthreads();
    }
}

extern "C" void kernel_launch(void* const* d_in, const int* in_sizes, int n_in,
                              void* d_out, int out_size, void* d_ws, size_t ws_size,
                              hipStream_t stream) {
    const float* x    = (const float*)d_in[0];
    const float* W    = (const float*)d_in[1];
    const float* bias = (const float*)d_in[2];
    const float* h0   = (const float*)d_in[3];
    const float* c0   = (const float*)d_in[4];
    float* out = (float*)d_out;

    float*    wt   = (float*)d_ws;
    float*    hbuf = wt + WT_FLOATS;
    unsigned* ctr  = (unsigned*)(hbuf + HBUF_FLOATS);

    hipMemsetAsync(ctr, 0, NCTR * CTR_STRIDE * sizeof(unsigned), stream);
    extract_weights<<<256, 256, 0, stream>>>(W, wt);

    void* args[] = { (void*)&x, (void*)&bias, (void*)&h0, (void*)&c0,
                     (void*)&wt, (void*)&hbuf, (void*)&ctr, (void*)&out };
    hipLaunchCooperativeKernel((const void*)lstm_coop, dim3(NBLK), dim3(NTHR),
                               args, 0, stream);
}